// Round 10
// baseline (515.340 us; speedup 1.0000x reference)
//
#include <hip/hip_runtime.h>
#include <hip/hip_cooperative_groups.h>

namespace cg = cooperative_groups;

#define N_SEL 8192
#define SUB_SZ 32
#define N_SUB 256
#define N_GRAPH 64
#define N_FULL 12288
#define E_RAW 262144
#define N_PERS 4
#define D 128
#define EPSILON 0.1f
#define LAMB1 0.5f

#define CAP_E 96                     // raw-edge bin capacity per row (lambda~21)
#define OVF_CAP 8192                 // overflow list (expected use: 0)
#define GRID_B 1024                  // cooperative grid: 4 blocks/CU x 256 CUs
#define ROWS_PER_B (N_FULL / GRID_B) // 12 rows per block
#define COS_BASE (GRID_B - N_SUB)    // blocks [768,1024) run the cosine units

typedef float f4_t __attribute__((ext_vector_type(4)));

// ---- workspace layout ----
#define OFF_COUNTS   0
#define OFF_INVMAP   ((size_t)N_FULL * 4)
#define OFF_ATTR     (OFF_INVMAP + (size_t)N_FULL * 4)
#define OFF_RAWCOLS  (OFF_ATTR + (size_t)N_SEL * SUB_SZ * 4)
#define OFF_OVFCNT   (OFF_RAWCOLS + (size_t)N_FULL * CAP_E * 4)
#define OFF_OVF      (OFF_OVFCNT + 16)
#define WS_NEEDED    (OFF_OVF + (size_t)OVF_CAP * 8)

// One cooperative kernel: init -> sync -> build -> sync -> rowfill(+patch) -> sync -> ovf.
__global__ __launch_bounds__(256, 4) void fused_kernel(
        const float* __restrict__ x,
        const float* __restrict__ Wc,
        const float* __restrict__ sscore,
        const int*   __restrict__ smap,
        const int*   __restrict__ rei,
        int*   __restrict__ counts,
        int*   __restrict__ inv_map,
        float* __restrict__ attr_vals,
        int*   __restrict__ raw_cols,
        int*   __restrict__ ovf_cnt,
        uint2* __restrict__ ovf,
        float* __restrict__ out)
{
    cg::grid_group grid = cg::this_grid();
    const int tid = threadIdx.x;
    const int b   = blockIdx.x;

    __shared__ float xs[SUB_SZ][D + 1];      // 16.5 KB (cosine phase)
    __shared__ float w2v[N_PERS][D];         // 2 KB
    __shared__ float rnorm[N_PERS][SUB_SZ];  // 0.5 KB
    __shared__ float rowscore;
    __shared__ unsigned ecol[CAP_E + SUB_SZ];
    __shared__ float    evalv[CAP_E + SUB_SZ];
    __shared__ int nloc;

    // ---------------- phase 0: init ws ----------------
    for (int t = b * 256 + tid; t < N_FULL; t += GRID_B * 256) {
        counts[t]  = 0;
        inv_map[t] = -1;
    }
    if (b == 0 && tid == 0) *ovf_cnt = 0;
    grid.sync();

    // ---------------- phase A: build ----------------
    // raw edges: exactly one 256-edge stripe per block (E_RAW/256 == GRID_B)
    {
        int e = b * 256 + tid;
        int r = rei[e];
        int c = rei[E_RAW + e];
        int slot = atomicAdd(&counts[r], 1);
        if (slot < CAP_E) {
            raw_cols[(size_t)r * CAP_E + slot] = c;
        } else {
            int o = atomicAdd(ovf_cnt, 1);
            if (o < OVF_CAP) ovf[o] = make_uint2((unsigned)r, (unsigned)c);
        }
    }
    // cosine units on blocks [COS_BASE, GRID_B)
    if (b >= COS_BASE) {
        const int s    = b - COS_BASE;
        const int base = s * SUB_SZ;

        for (int k = tid; k < SUB_SZ * D; k += 256) {
            int i = k >> 7;
            int d = k & (D - 1);
            xs[i][d] = x[(base + i) * D + d];
        }
        for (int k = tid; k < N_PERS * D; k += 256) {
            float w = Wc[k];
            ((float*)w2v)[k] = w * w;
        }
        if (tid < SUB_SZ) inv_map[smap[base + tid]] = base + tid;
        if (tid == 0) {
            int g4 = (s >> 2) << 2;
            float sum = sscore[g4] + sscore[g4 + 1] + sscore[g4 + 2] + sscore[g4 + 3];
            rowscore = (sscore[s] / sum) * LAMB1;
        }
        __syncthreads();

        if (tid < N_PERS * SUB_SZ) {
            int p = tid >> 5;
            int i = tid & 31;
            float acc = 0.f;
            #pragma unroll 8
            for (int d = 0; d < D; ++d) {
                float v = xs[i][d];
                acc = fmaf(v * v, w2v[p][d], acc);
            }
            rnorm[p][i] = 1.0f / fmaxf(sqrtf(acc), 1e-12f);
        }
        __syncthreads();

        for (int e = tid; e < SUB_SZ * SUB_SZ; e += 256) {
            int i = e >> 5;
            int j = e & 31;
            float v = 0.f;
            if (i != j) {
                float a0 = 0.f, a1 = 0.f, a2 = 0.f, a3 = 0.f;
                #pragma unroll 8
                for (int d = 0; d < D; ++d) {
                    float prod = xs[i][d] * xs[j][d];
                    a0 = fmaf(prod, w2v[0][d], a0);
                    a1 = fmaf(prod, w2v[1][d], a1);
                    a2 = fmaf(prod, w2v[2][d], a2);
                    a3 = fmaf(prod, w2v[3][d], a3);
                }
                float adj = 0.25f * (a0 * rnorm[0][i] * rnorm[0][j] +
                                     a1 * rnorm[1][i] * rnorm[1][j] +
                                     a2 * rnorm[2][i] * rnorm[2][j] +
                                     a3 * rnorm[3][i] * rnorm[3][j]);
                if (adj > EPSILON) v = adj * rowscore;
            }
            attr_vals[(size_t)base * SUB_SZ + e] = v;
        }
    }
    grid.sync();

    // ---------------- phase B: per-row zero-stream + ordered patch ----------------
    const f4_t z = (f4_t){0.f, 0.f, 0.f, 0.f};
    for (int r = b * ROWS_PER_B; r < (b + 1) * ROWS_PER_B; ++r) {
        int cnt = counts[r];
        if (cnt > CAP_E) cnt = CAP_E;
        if (tid == 0) nloc = cnt;
        __syncthreads();                       // nloc init visible

        if (tid < cnt) {
            ecol[tid]  = (unsigned)raw_cols[(size_t)r * CAP_E + tid];
            evalv[tid] = 1.0f - LAMB1;
        }
        int i = inv_map[r];
        if (i >= 0 && tid < SUB_SZ) {
            float v = attr_vals[(size_t)i * SUB_SZ + tid];
            if (v != 0.f) {
                int s2 = atomicAdd(&nloc, 1);
                ecol[s2]  = (unsigned)smap[(i >> 5) * SUB_SZ + tid];
                evalv[s2] = v;
            }
        }

        // zero-stream the whole row (regular stores: lines stay in L2 for patch)
        f4_t* dst = (f4_t*)(out + (size_t)r * N_FULL);
        #pragma unroll
        for (int k = 0; k < N_FULL / 4 / 256; ++k)   // 12
            dst[k * 256 + tid] = z;

        __syncthreads();                       // drains stores; ents complete

        int n = nloc;
        float* base = out + (size_t)r * N_FULL;
        for (int e = tid; e < n; e += 256)
            atomicAdd(&base[ecol[e]], evalv[e]);     // L2-hit RMWs, same block
        __syncthreads();                       // protect LDS reuse next row
    }
    grid.sync();

    // ---------------- phase C: overflow (expected 0) ----------------
    int n = *ovf_cnt;
    if (n > OVF_CAP) n = OVF_CAP;
    for (int t = b * 256 + tid; t < n; t += GRID_B * 256) {
        uint2 e = ovf[t];
        atomicAdd(&out[(size_t)e.x * N_FULL + e.y], 1.0f - LAMB1);
    }
}

// ---------------- fallback path (R3): zero fill + atomic scatter ----------------
#define N4_TOTAL 37748736
#define FILL_BLOCKS 4096
#define PER_BLOCK (N4_TOTAL / FILL_BLOCKS)
#define FILL_ITERS (PER_BLOCK / 256)

__global__ __launch_bounds__(256) void zero_kernel(f4_t* __restrict__ out)
{
    size_t base = (size_t)blockIdx.x * PER_BLOCK + threadIdx.x;
    const f4_t z = (f4_t){0.f, 0.f, 0.f, 0.f};
    #pragma unroll
    for (int k = 0; k < FILL_ITERS; ++k)
        __builtin_nontemporal_store(z, &out[base + (size_t)k * 256]);
}

__global__ __launch_bounds__(256) void scatter_kernel(
        const float* __restrict__ x,
        const float* __restrict__ Wc,
        const float* __restrict__ sscore,
        const int*   __restrict__ smap,
        const int*   __restrict__ rei,
        float* __restrict__ out)
{
    const int tid = threadIdx.x;

    if (blockIdx.x >= N_SUB) {
        int e = (blockIdx.x - N_SUB) * 256 + tid;
        long long r = rei[e];
        long long c = rei[E_RAW + e];
        atomicAdd(&out[r * (long long)N_FULL + c], 1.0f - LAMB1);
        return;
    }

    const int s    = blockIdx.x;
    const int base = s * SUB_SZ;

    __shared__ float xs[SUB_SZ][D + 1];
    __shared__ float w2[N_PERS][D];
    __shared__ float rnorm[N_PERS][SUB_SZ];
    __shared__ int   map_s[SUB_SZ];
    __shared__ float rowscore;

    for (int k = tid; k < SUB_SZ * D; k += 256) {
        int i = k >> 7;
        int d = k & (D - 1);
        xs[i][d] = x[(base + i) * D + d];
    }
    for (int k = tid; k < N_PERS * D; k += 256) {
        float w = Wc[k];
        ((float*)w2)[k] = w * w;
    }
    if (tid < SUB_SZ) map_s[tid] = smap[base + tid];
    if (tid == 0) {
        int g4 = (s >> 2) << 2;
        float sum = sscore[g4] + sscore[g4 + 1] + sscore[g4 + 2] + sscore[g4 + 3];
        rowscore = (sscore[s] / sum) * LAMB1;
    }
    __syncthreads();

    if (tid < N_PERS * SUB_SZ) {
        int p = tid >> 5;
        int i = tid & 31;
        float acc = 0.f;
        #pragma unroll 8
        for (int d = 0; d < D; ++d) {
            float v = xs[i][d];
            acc = fmaf(v * v, w2[p][d], acc);
        }
        rnorm[p][i] = 1.0f / fmaxf(sqrtf(acc), 1e-12f);
    }
    __syncthreads();

    for (int e = tid; e < SUB_SZ * SUB_SZ; e += 256) {
        int i = e >> 5;
        int j = e & 31;
        if (i == j) continue;
        float a0 = 0.f, a1 = 0.f, a2 = 0.f, a3 = 0.f;
        #pragma unroll 8
        for (int d = 0; d < D; ++d) {
            float prod = xs[i][d] * xs[j][d];
            a0 = fmaf(prod, w2[0][d], a0);
            a1 = fmaf(prod, w2[1][d], a1);
            a2 = fmaf(prod, w2[2][d], a2);
            a3 = fmaf(prod, w2[3][d], a3);
        }
        float adj = 0.25f * (a0 * rnorm[0][i] * rnorm[0][j] +
                             a1 * rnorm[1][i] * rnorm[1][j] +
                             a2 * rnorm[2][i] * rnorm[2][j] +
                             a3 * rnorm[3][i] * rnorm[3][j]);
        if (adj > EPSILON) {
            long long row = map_s[i];
            long long col = map_s[j];
            atomicAdd(&out[row * (long long)N_FULL + col], adj * rowscore);
        }
    }
}

extern "C" void kernel_launch(void* const* d_in, const int* in_sizes, int n_in,
                              void* d_out, int out_size, void* d_ws, size_t ws_size,
                              hipStream_t stream) {
    const float* x      = (const float*)d_in[0];
    const float* Wc     = (const float*)d_in[1];
    const float* sscore = (const float*)d_in[2];
    const int* smap = (const int*)d_in[4];
    const int* rei  = (const int*)d_in[7];
    float* out = (float*)d_out;

    bool coop_ok = false;
    if (ws_size >= WS_NEEDED) {
        char* ws = (char*)d_ws;
        int*   counts    = (int*)(ws + OFF_COUNTS);
        int*   inv_map   = (int*)(ws + OFF_INVMAP);
        float* attr_vals = (float*)(ws + OFF_ATTR);
        int*   raw_cols  = (int*)(ws + OFF_RAWCOLS);
        int*   ovf_cnt   = (int*)(ws + OFF_OVFCNT);
        uint2* ovf       = (uint2*)(ws + OFF_OVF);

        void* args[] = {
            (void*)&x, (void*)&Wc, (void*)&sscore, (void*)&smap, (void*)&rei,
            (void*)&counts, (void*)&inv_map, (void*)&attr_vals, (void*)&raw_cols,
            (void*)&ovf_cnt, (void*)&ovf, (void*)&out
        };
        hipError_t err = hipLaunchCooperativeKernel(
            (void*)fused_kernel, dim3(GRID_B), dim3(256), args, 0, stream);
        coop_ok = (err == hipSuccess);
    }

    if (!coop_ok) {
        // R3 fallback: NT contiguous fill + merged atomic scatter
        zero_kernel<<<FILL_BLOCKS, 256, 0, stream>>>((f4_t*)out);
        scatter_kernel<<<N_SUB + E_RAW / 256, 256, 0, stream>>>(
            x, Wc, sscore, smap, rei, out);
    }
}

// Round 11
// 155.785 us; speedup vs baseline: 3.3080x; 3.3080x over previous
//
#include <hip/hip_runtime.h>

#define N_SEL 8192
#define SUB_SZ 32
#define N_SUB 256
#define N_GRAPH 64
#define N_FULL 12288
#define E_RAW 262144
#define N_PERS 4
#define D 128
#define EPSILON 0.1f
#define LAMB1 0.5f

#define CAP_E 96                 // raw-edge bin capacity per row (lambda~21)
#define OVF_CAP 8192             // overflow list capacity (expected use: 0)
#define HALF (N_FULL / 2)        // 6144 floats = 24 KB per half-row block
#define NBLK (N_FULL * 2)        // 24576 half-row blocks
#define PER_XCD (NBLK / 8)       // 3072 contiguous half-rows per XCD

typedef float f4_t __attribute__((ext_vector_type(4)));

// ---- workspace layout ----
#define OFF_COUNTS   0
#define OFF_INVMAP   ((size_t)N_FULL * 4)
#define OFF_ATTR     (OFF_INVMAP + (size_t)N_FULL * 4)
#define OFF_RAWCOLS  (OFF_ATTR + (size_t)N_SEL * SUB_SZ * 4)
#define OFF_OVFCNT   (OFF_RAWCOLS + (size_t)N_FULL * CAP_E * 4)
#define OFF_OVF      (OFF_OVFCNT + 16)
#define WS_NEEDED    (OFF_OVF + (size_t)OVF_CAP * 8)

__global__ __launch_bounds__(256) void prep_kernel(int* __restrict__ counts,
                                                   int* __restrict__ inv_map,
                                                   int* __restrict__ ovf_cnt)
{
    int t = blockIdx.x * 256 + threadIdx.x;
    if (t < N_FULL) { counts[t] = 0; inv_map[t] = -1; }
    if (t == 0) *ovf_cnt = 0;
}

// Blocks [0,256): subgraph cosine blocks -> compact attr values + inv_map.
// Blocks [256,1280): raw edges -> per-row bins (cache-resident ~5 MB).
__global__ __launch_bounds__(256) void build_kernel(
        const float* __restrict__ x,
        const float* __restrict__ Wc,
        const float* __restrict__ sscore,
        const int*   __restrict__ smap,
        const int*   __restrict__ rei,
        int*   __restrict__ counts,
        int*   __restrict__ inv_map,
        float* __restrict__ attr_vals,
        int*   __restrict__ raw_cols,
        int*   __restrict__ ovf_cnt,
        uint2* __restrict__ ovf)
{
    const int tid = threadIdx.x;

    if (blockIdx.x >= N_SUB) {
        int e = (blockIdx.x - N_SUB) * 256 + tid;
        int r = rei[e];
        int c = rei[E_RAW + e];
        int slot = atomicAdd(&counts[r], 1);
        if (slot < CAP_E) {
            raw_cols[(size_t)r * CAP_E + slot] = c;
        } else {
            int o = atomicAdd(ovf_cnt, 1);
            if (o < OVF_CAP) ovf[o] = make_uint2((unsigned)r, (unsigned)c);
        }
        return;
    }

    const int s    = blockIdx.x;
    const int base = s * SUB_SZ;

    __shared__ float xs[SUB_SZ][D + 1];
    __shared__ float w2[N_PERS][D];
    __shared__ float rnorm[N_PERS][SUB_SZ];
    __shared__ float rowscore;

    for (int k = tid; k < SUB_SZ * D; k += 256) {
        int i = k >> 7;
        int d = k & (D - 1);
        xs[i][d] = x[(base + i) * D + d];
    }
    for (int k = tid; k < N_PERS * D; k += 256) {
        float w = Wc[k];
        ((float*)w2)[k] = w * w;
    }
    if (tid < SUB_SZ) inv_map[smap[base + tid]] = base + tid;
    if (tid == 0) {
        int g4 = (s >> 2) << 2;
        float sum = sscore[g4] + sscore[g4 + 1] + sscore[g4 + 2] + sscore[g4 + 3];
        rowscore = (sscore[s] / sum) * LAMB1;
    }
    __syncthreads();

    if (tid < N_PERS * SUB_SZ) {
        int p = tid >> 5;
        int i = tid & 31;
        float acc = 0.f;
        #pragma unroll 8
        for (int d = 0; d < D; ++d) {
            float v = xs[i][d];
            acc = fmaf(v * v, w2[p][d], acc);
        }
        rnorm[p][i] = 1.0f / fmaxf(sqrtf(acc), 1e-12f);
    }
    __syncthreads();

    for (int e = tid; e < SUB_SZ * SUB_SZ; e += 256) {
        int i = e >> 5;
        int j = e & 31;
        float v = 0.f;
        if (i != j) {
            float a0 = 0.f, a1 = 0.f, a2 = 0.f, a3 = 0.f;
            #pragma unroll 8
            for (int d = 0; d < D; ++d) {
                float prod = xs[i][d] * xs[j][d];
                a0 = fmaf(prod, w2[0][d], a0);
                a1 = fmaf(prod, w2[1][d], a1);
                a2 = fmaf(prod, w2[2][d], a2);
                a3 = fmaf(prod, w2[3][d], a3);
            }
            float adj = 0.25f * (a0 * rnorm[0][i] * rnorm[0][j] +
                                 a1 * rnorm[1][i] * rnorm[1][j] +
                                 a2 * rnorm[2][i] * rnorm[2][j] +
                                 a3 * rnorm[3][i] * rnorm[3][j]);
            if (adj > EPSILON) v = adj * rowscore;
        }
        attr_vals[(size_t)base * SUB_SZ + e] = v;
    }
}

// One block per HALF output row (24 KB LDS, 6 blocks/CU), R7 structure with
// ONE change: XCD-aware block swizzle so each XCD's resident blocks write a
// CONTIGUOUS 75 MB region (blockIdx round-robins XCDs on dispatch; sb maps
// XCD x -> half-rows [x*3072, (x+1)*3072)).
__global__ __launch_bounds__(256) void rowfill_kernel(
        const int*   __restrict__ counts,
        const int*   __restrict__ inv_map,
        const float* __restrict__ attr_vals,
        const int*   __restrict__ raw_cols,
        const int*   __restrict__ smap,
        float* __restrict__ out)
{
    __shared__ float row[HALF];              // 24 KB
    const int b0      = blockIdx.x;
    const int sb      = (b0 & 7) * PER_XCD + (b0 >> 3);   // XCD-contiguous
    const int r       = sb >> 1;
    const int colbase = (sb & 1) * HALF;
    const int tid     = threadIdx.x;

    f4_t* row4 = (f4_t*)row;
    const f4_t z = (f4_t){0.f, 0.f, 0.f, 0.f};
    #pragma unroll
    for (int k = 0; k < HALF / 4 / 256; ++k)       // 6 iters
        row4[tid + k * 256] = z;
    __syncthreads();

    // attr patch: this row's 31 cosine values (if row is a selected node)
    int i = inv_map[r];
    if (i >= 0 && tid < SUB_SZ) {
        float v = attr_vals[(size_t)i * SUB_SZ + tid];
        if (v != 0.f) {
            int c  = smap[(i >> 5) * SUB_SZ + tid];
            int lc = c - colbase;
            if ((unsigned)lc < HALF) atomicAdd(&row[lc], v);
        }
    }
    // raw-edge patch
    int cnt = counts[r];
    if (cnt > CAP_E) cnt = CAP_E;
    for (int e = tid; e < cnt; e += 256) {
        int c  = raw_cols[(size_t)r * CAP_E + e];
        int lc = c - colbase;
        if ((unsigned)lc < HALF) atomicAdd(&row[lc], 1.0f - LAMB1);
    }
    __syncthreads();

    f4_t* dst = (f4_t*)(out + (size_t)r * N_FULL + colbase);
    #pragma unroll
    for (int k = 0; k < HALF / 4 / 256; ++k)
        dst[tid + k * 256] = row4[tid + k * 256];  // regular stores
}

__global__ __launch_bounds__(256) void ovf_kernel(const int* __restrict__ ovf_cnt,
                                                  const uint2* __restrict__ ovf,
                                                  float* __restrict__ out)
{
    int n = *ovf_cnt;
    if (n > OVF_CAP) n = OVF_CAP;
    for (int t = blockIdx.x * 256 + threadIdx.x; t < n; t += gridDim.x * 256) {
        uint2 e = ovf[t];
        atomicAdd(&out[(size_t)e.x * N_FULL + e.y], 1.0f - LAMB1);
    }
}

// ---------------- fallback path (R3): zero fill + atomic scatter ----------------
#define N4_TOTAL 37748736
#define FILL_BLOCKS 4096
#define PER_BLOCK (N4_TOTAL / FILL_BLOCKS)
#define FILL_ITERS (PER_BLOCK / 256)

__global__ __launch_bounds__(256) void zero_kernel(f4_t* __restrict__ out)
{
    size_t base = (size_t)blockIdx.x * PER_BLOCK + threadIdx.x;
    const f4_t z = (f4_t){0.f, 0.f, 0.f, 0.f};
    #pragma unroll
    for (int k = 0; k < FILL_ITERS; ++k)
        __builtin_nontemporal_store(z, &out[base + (size_t)k * 256]);
}

__global__ __launch_bounds__(256) void scatter_kernel(
        const float* __restrict__ x,
        const float* __restrict__ Wc,
        const float* __restrict__ sscore,
        const int*   __restrict__ smap,
        const int*   __restrict__ rei,
        float* __restrict__ out)
{
    const int tid = threadIdx.x;

    if (blockIdx.x >= N_SUB) {
        int e = (blockIdx.x - N_SUB) * 256 + tid;
        long long r = rei[e];
        long long c = rei[E_RAW + e];
        atomicAdd(&out[r * (long long)N_FULL + c], 1.0f - LAMB1);
        return;
    }

    const int s    = blockIdx.x;
    const int base = s * SUB_SZ;

    __shared__ float xs[SUB_SZ][D + 1];
    __shared__ float w2[N_PERS][D];
    __shared__ float rnorm[N_PERS][SUB_SZ];
    __shared__ int   map_s[SUB_SZ];
    __shared__ float rowscore;

    for (int k = tid; k < SUB_SZ * D; k += 256) {
        int i = k >> 7;
        int d = k & (D - 1);
        xs[i][d] = x[(base + i) * D + d];
    }
    for (int k = tid; k < N_PERS * D; k += 256) {
        float w = Wc[k];
        ((float*)w2)[k] = w * w;
    }
    if (tid < SUB_SZ) map_s[tid] = smap[base + tid];
    if (tid == 0) {
        int g4 = (s >> 2) << 2;
        float sum = sscore[g4] + sscore[g4 + 1] + sscore[g4 + 2] + sscore[g4 + 3];
        rowscore = (sscore[s] / sum) * LAMB1;
    }
    __syncthreads();

    if (tid < N_PERS * SUB_SZ) {
        int p = tid >> 5;
        int i = tid & 31;
        float acc = 0.f;
        #pragma unroll 8
        for (int d = 0; d < D; ++d) {
            float v = xs[i][d];
            acc = fmaf(v * v, w2[p][d], acc);
        }
        rnorm[p][i] = 1.0f / fmaxf(sqrtf(acc), 1e-12f);
    }
    __syncthreads();

    for (int e = tid; e < SUB_SZ * SUB_SZ; e += 256) {
        int i = e >> 5;
        int j = e & 31;
        if (i == j) continue;
        float a0 = 0.f, a1 = 0.f, a2 = 0.f, a3 = 0.f;
        #pragma unroll 8
        for (int d = 0; d < D; ++d) {
            float prod = xs[i][d] * xs[j][d];
            a0 = fmaf(prod, w2[0][d], a0);
            a1 = fmaf(prod, w2[1][d], a1);
            a2 = fmaf(prod, w2[2][d], a2);
            a3 = fmaf(prod, w2[3][d], a3);
        }
        float adj = 0.25f * (a0 * rnorm[0][i] * rnorm[0][j] +
                             a1 * rnorm[1][i] * rnorm[1][j] +
                             a2 * rnorm[2][i] * rnorm[2][j] +
                             a3 * rnorm[3][i] * rnorm[3][j]);
        if (adj > EPSILON) {
            long long row = map_s[i];
            long long col = map_s[j];
            atomicAdd(&out[row * (long long)N_FULL + col], adj * rowscore);
        }
    }
}

extern "C" void kernel_launch(void* const* d_in, const int* in_sizes, int n_in,
                              void* d_out, int out_size, void* d_ws, size_t ws_size,
                              hipStream_t stream) {
    const float* x      = (const float*)d_in[0];
    const float* Wc     = (const float*)d_in[1];
    const float* sscore = (const float*)d_in[2];
    const int* smap = (const int*)d_in[4];
    const int* rei  = (const int*)d_in[7];
    float* out = (float*)d_out;

    if (ws_size >= WS_NEEDED) {
        char* ws = (char*)d_ws;
        int*   counts    = (int*)(ws + OFF_COUNTS);
        int*   inv_map   = (int*)(ws + OFF_INVMAP);
        float* attr_vals = (float*)(ws + OFF_ATTR);
        int*   raw_cols  = (int*)(ws + OFF_RAWCOLS);
        int*   ovf_cnt   = (int*)(ws + OFF_OVFCNT);
        uint2* ovf       = (uint2*)(ws + OFF_OVF);

        prep_kernel<<<(N_FULL + 255) / 256, 256, 0, stream>>>(counts, inv_map, ovf_cnt);
        build_kernel<<<N_SUB + E_RAW / 256, 256, 0, stream>>>(
            x, Wc, sscore, smap, rei, counts, inv_map, attr_vals, raw_cols, ovf_cnt, ovf);
        rowfill_kernel<<<NBLK, 256, 0, stream>>>(
            counts, inv_map, attr_vals, raw_cols, smap, out);
        ovf_kernel<<<16, 256, 0, stream>>>(ovf_cnt, ovf, out);
    } else {
        zero_kernel<<<FILL_BLOCKS, 256, 0, stream>>>((f4_t*)out);
        scatter_kernel<<<N_SUB + E_RAW / 256, 256, 0, stream>>>(
            x, Wc, sscore, smap, rei, out);
    }
}

// Round 12
// 152.098 us; speedup vs baseline: 3.3882x; 1.0242x over previous
//
#include <hip/hip_runtime.h>

#define N_SEL 8192
#define SUB_SZ 32
#define N_SUB 256
#define N_GRAPH 64
#define N_FULL 12288
#define E_RAW 262144
#define N_PERS 4
#define D 128
#define EPSILON 0.1f
#define LAMB1 0.5f

#define CAP_E 96                 // raw-edge bin capacity per row (lambda~21)
#define OVF_CAP 8192             // overflow list capacity (expected use: 0)
#define HALF (N_FULL / 2)        // 6144 floats = 24 KB per half-row block
#define NBLK (N_FULL * 2)        // 24576 half-row blocks
#define PER_XCD (NBLK / 8)       // 3072 contiguous half-rows per XCD

typedef float f4_t __attribute__((ext_vector_type(4)));

// ---- workspace layout ----
#define OFF_COUNTS   0
#define OFF_INVMAP   ((size_t)N_FULL * 4)
#define OFF_ATTR     (OFF_INVMAP + (size_t)N_FULL * 4)
#define OFF_RAWCOLS  (OFF_ATTR + (size_t)N_SEL * SUB_SZ * 4)
#define OFF_OVFCNT   (OFF_RAWCOLS + (size_t)N_FULL * CAP_E * 4)
#define OFF_OVF      (OFF_OVFCNT + 16)
#define WS_NEEDED    (OFF_OVF + (size_t)OVF_CAP * 8)

__global__ __launch_bounds__(256) void prep_kernel(int* __restrict__ counts,
                                                   int* __restrict__ inv_map,
                                                   int* __restrict__ ovf_cnt)
{
    int t = blockIdx.x * 256 + threadIdx.x;
    if (t < N_FULL) { counts[t] = 0; inv_map[t] = -1; }
    if (t == 0) *ovf_cnt = 0;
}

// Blocks [0,256): subgraph cosine blocks -> compact attr values + inv_map.
// Blocks [256,1280): raw edges -> per-row bins (cache-resident ~5 MB).
__global__ __launch_bounds__(256) void build_kernel(
        const float* __restrict__ x,
        const float* __restrict__ Wc,
        const float* __restrict__ sscore,
        const int*   __restrict__ smap,
        const int*   __restrict__ rei,
        int*   __restrict__ counts,
        int*   __restrict__ inv_map,
        float* __restrict__ attr_vals,
        int*   __restrict__ raw_cols,
        int*   __restrict__ ovf_cnt,
        uint2* __restrict__ ovf)
{
    const int tid = threadIdx.x;

    if (blockIdx.x >= N_SUB) {
        int e = (blockIdx.x - N_SUB) * 256 + tid;
        int r = rei[e];
        int c = rei[E_RAW + e];
        int slot = atomicAdd(&counts[r], 1);
        if (slot < CAP_E) {
            raw_cols[(size_t)r * CAP_E + slot] = c;
        } else {
            int o = atomicAdd(ovf_cnt, 1);
            if (o < OVF_CAP) ovf[o] = make_uint2((unsigned)r, (unsigned)c);
        }
        return;
    }

    const int s    = blockIdx.x;
    const int base = s * SUB_SZ;

    __shared__ float xs[SUB_SZ][D + 1];
    __shared__ float w2[N_PERS][D];
    __shared__ float rnorm[N_PERS][SUB_SZ];
    __shared__ float rowscore;

    for (int k = tid; k < SUB_SZ * D; k += 256) {
        int i = k >> 7;
        int d = k & (D - 1);
        xs[i][d] = x[(base + i) * D + d];
    }
    for (int k = tid; k < N_PERS * D; k += 256) {
        float w = Wc[k];
        ((float*)w2)[k] = w * w;
    }
    if (tid < SUB_SZ) inv_map[smap[base + tid]] = base + tid;
    if (tid == 0) {
        int g4 = (s >> 2) << 2;
        float sum = sscore[g4] + sscore[g4 + 1] + sscore[g4 + 2] + sscore[g4 + 3];
        rowscore = (sscore[s] / sum) * LAMB1;
    }
    __syncthreads();

    if (tid < N_PERS * SUB_SZ) {
        int p = tid >> 5;
        int i = tid & 31;
        float acc = 0.f;
        #pragma unroll 8
        for (int d = 0; d < D; ++d) {
            float v = xs[i][d];
            acc = fmaf(v * v, w2[p][d], acc);
        }
        rnorm[p][i] = 1.0f / fmaxf(sqrtf(acc), 1e-12f);
    }
    __syncthreads();

    for (int e = tid; e < SUB_SZ * SUB_SZ; e += 256) {
        int i = e >> 5;
        int j = e & 31;
        float v = 0.f;
        if (i != j) {
            float a0 = 0.f, a1 = 0.f, a2 = 0.f, a3 = 0.f;
            #pragma unroll 8
            for (int d = 0; d < D; ++d) {
                float prod = xs[i][d] * xs[j][d];
                a0 = fmaf(prod, w2[0][d], a0);
                a1 = fmaf(prod, w2[1][d], a1);
                a2 = fmaf(prod, w2[2][d], a2);
                a3 = fmaf(prod, w2[3][d], a3);
            }
            float adj = 0.25f * (a0 * rnorm[0][i] * rnorm[0][j] +
                                 a1 * rnorm[1][i] * rnorm[1][j] +
                                 a2 * rnorm[2][i] * rnorm[2][j] +
                                 a3 * rnorm[3][i] * rnorm[3][j]);
            if (adj > EPSILON) v = adj * rowscore;
        }
        attr_vals[(size_t)base * SUB_SZ + e] = v;
    }
}

// One block per HALF output row (24 KB LDS), XCD-contiguous swizzle (R11),
// final stream with NONTEMPORAL stores (the single change vs R11).
__global__ __launch_bounds__(256) void rowfill_kernel(
        const int*   __restrict__ counts,
        const int*   __restrict__ inv_map,
        const float* __restrict__ attr_vals,
        const int*   __restrict__ raw_cols,
        const int*   __restrict__ smap,
        float* __restrict__ out)
{
    __shared__ float row[HALF];              // 24 KB
    const int b0      = blockIdx.x;
    const int sb      = (b0 & 7) * PER_XCD + (b0 >> 3);   // XCD-contiguous
    const int r       = sb >> 1;
    const int colbase = (sb & 1) * HALF;
    const int tid     = threadIdx.x;

    f4_t* row4 = (f4_t*)row;
    const f4_t z = (f4_t){0.f, 0.f, 0.f, 0.f};
    #pragma unroll
    for (int k = 0; k < HALF / 4 / 256; ++k)       // 6 iters
        row4[tid + k * 256] = z;
    __syncthreads();

    // attr patch: this row's 31 cosine values (if row is a selected node)
    int i = inv_map[r];
    if (i >= 0 && tid < SUB_SZ) {
        float v = attr_vals[(size_t)i * SUB_SZ + tid];
        if (v != 0.f) {
            int c  = smap[(i >> 5) * SUB_SZ + tid];
            int lc = c - colbase;
            if ((unsigned)lc < HALF) atomicAdd(&row[lc], v);
        }
    }
    // raw-edge patch
    int cnt = counts[r];
    if (cnt > CAP_E) cnt = CAP_E;
    for (int e = tid; e < cnt; e += 256) {
        int c  = raw_cols[(size_t)r * CAP_E + e];
        int lc = c - colbase;
        if ((unsigned)lc < HALF) atomicAdd(&row[lc], 1.0f - LAMB1);
    }
    __syncthreads();

    f4_t* dst = (f4_t*)(out + (size_t)r * N_FULL + colbase);
    #pragma unroll
    for (int k = 0; k < HALF / 4 / 256; ++k)
        __builtin_nontemporal_store(row4[tid + k * 256], &dst[tid + k * 256]);
}

__global__ __launch_bounds__(256) void ovf_kernel(const int* __restrict__ ovf_cnt,
                                                  const uint2* __restrict__ ovf,
                                                  float* __restrict__ out)
{
    int n = *ovf_cnt;
    if (n > OVF_CAP) n = OVF_CAP;
    for (int t = blockIdx.x * 256 + threadIdx.x; t < n; t += gridDim.x * 256) {
        uint2 e = ovf[t];
        atomicAdd(&out[(size_t)e.x * N_FULL + e.y], 1.0f - LAMB1);
    }
}

// ---------------- fallback path (R3): zero fill + atomic scatter ----------------
#define N4_TOTAL 37748736
#define FILL_BLOCKS 4096
#define PER_BLOCK (N4_TOTAL / FILL_BLOCKS)
#define FILL_ITERS (PER_BLOCK / 256)

__global__ __launch_bounds__(256) void zero_kernel(f4_t* __restrict__ out)
{
    size_t base = (size_t)blockIdx.x * PER_BLOCK + threadIdx.x;
    const f4_t z = (f4_t){0.f, 0.f, 0.f, 0.f};
    #pragma unroll
    for (int k = 0; k < FILL_ITERS; ++k)
        __builtin_nontemporal_store(z, &out[base + (size_t)k * 256]);
}

__global__ __launch_bounds__(256) void scatter_kernel(
        const float* __restrict__ x,
        const float* __restrict__ Wc,
        const float* __restrict__ sscore,
        const int*   __restrict__ smap,
        const int*   __restrict__ rei,
        float* __restrict__ out)
{
    const int tid = threadIdx.x;

    if (blockIdx.x >= N_SUB) {
        int e = (blockIdx.x - N_SUB) * 256 + tid;
        long long r = rei[e];
        long long c = rei[E_RAW + e];
        atomicAdd(&out[r * (long long)N_FULL + c], 1.0f - LAMB1);
        return;
    }

    const int s    = blockIdx.x;
    const int base = s * SUB_SZ;

    __shared__ float xs[SUB_SZ][D + 1];
    __shared__ float w2[N_PERS][D];
    __shared__ float rnorm[N_PERS][SUB_SZ];
    __shared__ int   map_s[SUB_SZ];
    __shared__ float rowscore;

    for (int k = tid; k < SUB_SZ * D; k += 256) {
        int i = k >> 7;
        int d = k & (D - 1);
        xs[i][d] = x[(base + i) * D + d];
    }
    for (int k = tid; k < N_PERS * D; k += 256) {
        float w = Wc[k];
        ((float*)w2)[k] = w * w;
    }
    if (tid < SUB_SZ) map_s[tid] = smap[base + tid];
    if (tid == 0) {
        int g4 = (s >> 2) << 2;
        float sum = sscore[g4] + sscore[g4 + 1] + sscore[g4 + 2] + sscore[g4 + 3];
        rowscore = (sscore[s] / sum) * LAMB1;
    }
    __syncthreads();

    if (tid < N_PERS * SUB_SZ) {
        int p = tid >> 5;
        int i = tid & 31;
        float acc = 0.f;
        #pragma unroll 8
        for (int d = 0; d < D; ++d) {
            float v = xs[i][d];
            acc = fmaf(v * v, w2[p][d], acc);
        }
        rnorm[p][i] = 1.0f / fmaxf(sqrtf(acc), 1e-12f);
    }
    __syncthreads();

    for (int e = tid; e < SUB_SZ * SUB_SZ; e += 256) {
        int i = e >> 5;
        int j = e & 31;
        if (i == j) continue;
        float a0 = 0.f, a1 = 0.f, a2 = 0.f, a3 = 0.f;
        #pragma unroll 8
        for (int d = 0; d < D; ++d) {
            float prod = xs[i][d] * xs[j][d];
            a0 = fmaf(prod, w2[0][d], a0);
            a1 = fmaf(prod, w2[1][d], a1);
            a2 = fmaf(prod, w2[2][d], a2);
            a3 = fmaf(prod, w2[3][d], a3);
        }
        float adj = 0.25f * (a0 * rnorm[0][i] * rnorm[0][j] +
                             a1 * rnorm[1][i] * rnorm[1][j] +
                             a2 * rnorm[2][i] * rnorm[2][j] +
                             a3 * rnorm[3][i] * rnorm[3][j]);
        if (adj > EPSILON) {
            long long row = map_s[i];
            long long col = map_s[j];
            atomicAdd(&out[row * (long long)N_FULL + col], adj * rowscore);
        }
    }
}

extern "C" void kernel_launch(void* const* d_in, const int* in_sizes, int n_in,
                              void* d_out, int out_size, void* d_ws, size_t ws_size,
                              hipStream_t stream) {
    const float* x      = (const float*)d_in[0];
    const float* Wc     = (const float*)d_in[1];
    const float* sscore = (const float*)d_in[2];
    const int* smap = (const int*)d_in[4];
    const int* rei  = (const int*)d_in[7];
    float* out = (float*)d_out;

    if (ws_size >= WS_NEEDED) {
        char* ws = (char*)d_ws;
        int*   counts    = (int*)(ws + OFF_COUNTS);
        int*   inv_map   = (int*)(ws + OFF_INVMAP);
        float* attr_vals = (float*)(ws + OFF_ATTR);
        int*   raw_cols  = (int*)(ws + OFF_RAWCOLS);
        int*   ovf_cnt   = (int*)(ws + OFF_OVFCNT);
        uint2* ovf       = (uint2*)(ws + OFF_OVF);

        prep_kernel<<<(N_FULL + 255) / 256, 256, 0, stream>>>(counts, inv_map, ovf_cnt);
        build_kernel<<<N_SUB + E_RAW / 256, 256, 0, stream>>>(
            x, Wc, sscore, smap, rei, counts, inv_map, attr_vals, raw_cols, ovf_cnt, ovf);
        rowfill_kernel<<<NBLK, 256, 0, stream>>>(
            counts, inv_map, attr_vals, raw_cols, smap, out);
        ovf_kernel<<<16, 256, 0, stream>>>(ovf_cnt, ovf, out);
    } else {
        zero_kernel<<<FILL_BLOCKS, 256, 0, stream>>>((f4_t*)out);
        scatter_kernel<<<N_SUB + E_RAW / 256, 256, 0, stream>>>(
            x, Wc, sscore, smap, rei, out);
    }
}